// Round 9
// baseline (169.122 us; speedup 1.0000x reference)
//
#include <hip/hip_runtime.h>
#include <math.h>

typedef __bf16 bf16;
typedef __bf16 bf16x8 __attribute__((ext_vector_type(8)));
typedef float  f32x4  __attribute__((ext_vector_type(4)));

#define DEV __device__ __forceinline__
#define VMCNT(n) asm volatile("s_waitcnt vmcnt(" #n ")" ::: "memory")
#define CFENCE  asm volatile("" ::: "memory")
#define BAR()   { CFENCE; __builtin_amdgcn_s_barrier(); CFENCE; }

DEV void gload_lds16(const bf16* g, bf16* l) {
  __builtin_amdgcn_global_load_lds(
      (const __attribute__((address_space(1))) void*)g,
      (__attribute__((address_space(3))) void*)l, 16, 0, 0);
}

// ---------------- workspace layout (bytes) ----------------
#define OFF_STATS 0UL
#define OFF_WOT   1024UL        // 512*512*2 = 524288            -> 525312
#define OFF_BIASQ 525312UL      // 1536*4    = 6144              -> 531456
#define OFF_WTQKV 531456UL      // 1536*512*2 = 1572864          -> 2104320
#define OFF_XN    2104320UL     // 8192*512*2 = 8388608          -> 10492928
#define OFF_QKV   10492928UL    // 8192*1536*2 = 25165824        -> 35658752
#define OFF_VT    35658752UL    // 2*512*4096*2 = 8388608        -> 44047360
#define OFF_S     44047360UL    // 2*4096*4096*2 = 67108864      -> 111156224
#define OFF_INVL  111156224UL   // 8192*4 = 32768                -> 111188992
// overlays (stream-ordered lifetimes):
#define OFF_ATTN  2104320UL     // overlays xn (dead after QKV); PV writes here
                                // while reading S -> no aliasing with S.
#define OFF_GNP   44047360UL    // gn partials, prep-time only (S written later)

// ---------------- GroupNorm partial stats: 1024 blocks ----------------
__global__ __launch_bounds__(256) void gn_part_k(const float* __restrict__ x,
                                                 float2* __restrict__ part) {
  const int blk = blockIdx.x;
  const int chunk = blk & 15;
  const int bg = blk >> 4;
  const int b = bg >> 5, g = bg & 31;
  const int t = threadIdx.x;
  const int p = chunk * 256 + t;
  const float* xp = x + (size_t)b * (4096 * 512) + (size_t)p * 512 + g * 16;
  float4 v0 = *(const float4*)(xp);
  float4 v1 = *(const float4*)(xp + 4);
  float4 v2 = *(const float4*)(xp + 8);
  float4 v3 = *(const float4*)(xp + 12);
  float s  = v0.x + v0.y + v0.z + v0.w + v1.x + v1.y + v1.z + v1.w
           + v2.x + v2.y + v2.z + v2.w + v3.x + v3.y + v3.z + v3.w;
  float ss = v0.x*v0.x + v0.y*v0.y + v0.z*v0.z + v0.w*v0.w
           + v1.x*v1.x + v1.y*v1.y + v1.z*v1.z + v1.w*v1.w
           + v2.x*v2.x + v2.y*v2.y + v2.z*v2.z + v2.w*v2.w
           + v3.x*v3.x + v3.y*v3.y + v3.z*v3.z + v3.w*v3.w;
#pragma unroll
  for (int off = 32; off; off >>= 1) {
    s  += __shfl_xor(s, off);
    ss += __shfl_xor(ss, off);
  }
  __shared__ float rs[4], rss[4];
  const int w = t >> 6, l = t & 63;
  if (l == 0) { rs[w] = s; rss[w] = ss; }
  __syncthreads();
  if (t == 0)
    part[blk] = make_float2(rs[0] + rs[1] + rs[2] + rs[3],
                            rss[0] + rss[1] + rss[2] + rss[3]);
}

__global__ void gn_finish_k(const float2* __restrict__ part,
                            float2* __restrict__ stats) {
  const int g = threadIdx.x;
  float s = 0.f, ss = 0.f;
#pragma unroll
  for (int c = 0; c < 16; ++c) {
    float2 p = part[g * 16 + c];
    s += p.x; ss += p.y;
  }
  float mean = s * (1.0f / 65536.0f);
  float var  = ss * (1.0f / 65536.0f) - mean * mean;
  stats[g] = make_float2(mean, 1.0f / sqrtf(var + 1e-6f));
}

// ---------------- normalize + bf16 cast ----------------
__global__ __launch_bounds__(256) void gn_apply_k(const float* __restrict__ x,
                                                  const float2* __restrict__ stats,
                                                  const float* __restrict__ gamma,
                                                  const float* __restrict__ beta,
                                                  bf16* __restrict__ xn) {
  size_t i = ((size_t)blockIdx.x * 256 + threadIdx.x) * 8;
  const int c = (int)(i & 511);
  const int b = (int)(i >> 21);
  float2 st = stats[b * 32 + (c >> 4)];
  float4 xa = *(const float4*)(x + i);
  float4 xb = *(const float4*)(x + i + 4);
  float4 ga = *(const float4*)(gamma + c);
  float4 gb = *(const float4*)(gamma + c + 4);
  float4 ba = *(const float4*)(beta + c);
  float4 bb = *(const float4*)(beta + c + 4);
  bf16x8 o;
  o[0] = (bf16)((xa.x - st.x) * st.y * ga.x + ba.x);
  o[1] = (bf16)((xa.y - st.x) * st.y * ga.y + ba.y);
  o[2] = (bf16)((xa.z - st.x) * st.y * ga.z + ba.z);
  o[3] = (bf16)((xa.w - st.x) * st.y * ga.w + ba.w);
  o[4] = (bf16)((xb.x - st.x) * st.y * gb.x + bb.x);
  o[5] = (bf16)((xb.y - st.x) * st.y * gb.y + bb.y);
  o[6] = (bf16)((xb.z - st.x) * st.y * gb.z + bb.z);
  o[7] = (bf16)((xb.w - st.x) * st.y * gb.w + bb.w);
  *(bf16x8*)(xn + i) = o;
}

// ---------------- weight transpose + bf16 convert ----------------
__global__ void prep_w_k(const float* __restrict__ wq, const float* __restrict__ wk,
                         const float* __restrict__ wv, const float* __restrict__ wo,
                         bf16* __restrict__ wt_qkv, bf16* __restrict__ wot, float qscale) {
  const int z = blockIdx.z;
  const float* W = (z == 0) ? wq : (z == 1) ? wk : (z == 2) ? wv : wo;
  bf16* dst = (z < 3) ? (wt_qkv + (size_t)z * 512 * 512) : wot;
  const float s = (z == 0) ? qscale : 1.0f;
  __shared__ float tile[32][33];
  const int i0 = blockIdx.y * 32;
  const int o0 = blockIdx.x * 32;
#pragma unroll
  for (int r = threadIdx.y; r < 32; r += 8)
    tile[r][threadIdx.x] = W[(size_t)(i0 + r) * 512 + o0 + threadIdx.x];
  __syncthreads();
#pragma unroll
  for (int r = threadIdx.y; r < 32; r += 8)
    dst[(size_t)(o0 + r) * 512 + i0 + threadIdx.x] = (bf16)(tile[threadIdx.x][r] * s);
}

__global__ void prep_bias_k(const float* __restrict__ bq, const float* __restrict__ bk,
                            const float* __restrict__ bv, float* __restrict__ bias_qkv,
                            float qscale) {
  int i = blockIdx.x * 256 + threadIdx.x;
  float v = (i < 512) ? bq[i] * qscale : (i < 1024) ? bk[i - 512] : bv[i - 1024];
  bias_qkv[i] = v;
}

// ---------------- V transpose ----------------
__global__ void transpose_v_k(const bf16* __restrict__ qkv, bf16* __restrict__ vt) {
  __shared__ bf16 tile[32][33];
  const int z = blockIdx.z;
  const int n0 = blockIdx.x * 32, d0 = blockIdx.y * 32;
  const bf16* src = qkv + (size_t)z * 4096 * 1536 + 1024;
#pragma unroll
  for (int r = threadIdx.y; r < 32; r += 8)
    tile[r][threadIdx.x] = src[(size_t)(n0 + r) * 1536 + d0 + threadIdx.x];
  __syncthreads();
  bf16* dst = vt + (size_t)z * 512 * 4096;
#pragma unroll
  for (int r = threadIdx.y; r < 32; r += 8)
    dst[(size_t)(d0 + r) * 4096 + n0 + threadIdx.x] = tile[threadIdx.x][r];
}

// ---------------- row sum of P: invl[r] = 1 / sum_c P[r,c] ----------------
// Reads the bf16-ROUNDED P that PV will consume -> normalization is exactly
// consistent (kills the f32-vs-bf16 lsum mismatch that inflated absmax).
__global__ __launch_bounds__(256) void rowsum_k(const bf16* __restrict__ S,
                                                float* __restrict__ invl) {
  const int r = blockIdx.x;                 // 0..8191
  const bf16* p = S + (size_t)r * 4096 + threadIdx.x * 16;
  bf16x8 u0 = *(const bf16x8*)p;
  bf16x8 u1 = *(const bf16x8*)(p + 8);
  float s = 0.f;
#pragma unroll
  for (int j = 0; j < 8; ++j) s += (float)u0[j] + (float)u1[j];
#pragma unroll
  for (int off = 32; off; off >>= 1) s += __shfl_xor(s, off);
  __shared__ float red[4];
  const int w = threadIdx.x >> 6, l = threadIdx.x & 63;
  if (l == 0) red[w] = s;
  __syncthreads();
  if (threadIdx.x == 0)
    invl[r] = 1.0f / (red[0] + red[1] + red[2] + red[3]);
}

// ---------------- NT bf16 MFMA GEMM: BK=64, XOR-swizzled LDS (2-phase) -----
// EPI: 0 bf16; 1 +bias bf16; 2 +bias+resid f32; 5 *invl[row] bf16 (bias=invl)
template <int BM, int BN, int EPI, int GX, int GY, int GZ>
__global__ __launch_bounds__(256, 2) void gemm_nt(
    const bf16* __restrict__ A, int lda, long sAz,
    const bf16* __restrict__ B, int ldb, long sBz,
    void* __restrict__ C, int ldc, long sCz,
    int nk,
    const float* __restrict__ bias,
    const float* __restrict__ resid) {
  constexpr int WM = BM / 2, WN = BN / 2;
  constexpr int FM = BM / 32, FN = BN / 32;
  constexpr int NWG = GX * GY * GZ;
  constexpr int CPX = NWG / 8;
  __shared__ alignas(16) bf16 As[2][BM * 64];
  __shared__ alignas(16) bf16 Bs[2][BN * 64];

  const int lin = blockIdx.x;
  const int wid = (lin & 7) * CPX + (lin >> 3);
  const int bx = wid % GX;
  const int by = (wid / GX) % GY;
  const int bz = wid / (GX * GY);

  const int t = threadIdx.x;
  const bf16* Aq = A + (size_t)bz * sAz + (size_t)by * BM * lda;
  const bf16* Bq = B + (size_t)bz * sBz + (size_t)bx * BN * ldb;

  const int srow = t >> 3;
  const int sg   = (t & 7) ^ (srow & 7);

  auto stage = [&](int buf, int kt) {
    const int k0 = kt * 64 + sg * 8;
#pragma unroll
    for (int i = 0; i < BM / 32; ++i)
      gload_lds16(Aq + (size_t)(i * 32 + srow) * lda + k0, &As[buf][i * 2048 + t * 8]);
#pragma unroll
    for (int i = 0; i < BN / 32; ++i)
      gload_lds16(Bq + (size_t)(i * 32 + srow) * ldb + k0, &Bs[buf][i * 2048 + t * 8]);
  };

  const int l = t & 63, w = t >> 6;
  const int wr = w >> 1, wc = w & 1;
  const int lr = l & 15, kh = l >> 4;
  const int rs = lr & 7;

  f32x4 acc[FM][FN] = {};

  stage(0, 0);
  for (int kt = 0; kt < nk; ++kt) {
    __syncthreads();
    if (kt + 1 < nk) stage((kt + 1) & 1, kt + 1);
    const int buf = kt & 1;
    bf16x8 a[2][FM], b[2][FN];
#pragma unroll
    for (int h = 0; h < 2; ++h) {
      const int g = ((h * 4 + kh) ^ rs) * 8;
#pragma unroll
      for (int m = 0; m < FM; ++m)
        a[h][m] = *(const bf16x8*)(&As[buf][(wr * WM + m * 16 + lr) * 64 + g]);
#pragma unroll
      for (int n = 0; n < FN; ++n)
        b[h][n] = *(const bf16x8*)(&Bs[buf][(wc * WN + n * 16 + lr) * 64 + g]);
    }
#pragma unroll
    for (int h = 0; h < 2; ++h)
#pragma unroll
      for (int m = 0; m < FM; ++m)
#pragma unroll
        for (int n = 0; n < FN; ++n)
          acc[m][n] = __builtin_amdgcn_mfma_f32_16x16x32_bf16(a[h][m], b[h][n], acc[m][n], 0, 0, 0);
  }

  const int gr0 = by * BM + wr * WM + kh * 4;
  const int gc0 = bx * BN + wc * WN + lr;
#pragma unroll
  for (int m = 0; m < FM; ++m)
#pragma unroll
    for (int n = 0; n < FN; ++n) {
      const int c = gc0 + n * 16;
      float bv = 0.f;
      if constexpr (EPI == 1 || EPI == 2) bv = bias[c];
#pragma unroll
      for (int j = 0; j < 4; ++j) {
        const int r = gr0 + m * 16 + j;
        float val = acc[m][n][j] + bv;
        if constexpr (EPI == 2) {
          float* Cf = (float*)C + (size_t)bz * sCz;
          Cf[(size_t)r * ldc + c] = val + resid[(size_t)r * ldc + c];
        } else if constexpr (EPI == 5) {
          bf16* Cb = (bf16*)C + (size_t)bz * sCz;
          Cb[(size_t)r * ldc + c] = (bf16)(acc[m][n][j] * bias[bz * 4096 + r]);
        } else {
          bf16* Cb = (bf16*)C + (size_t)bz * sCz;
          Cb[(size_t)r * ldc + c] = (bf16)val;
        }
      }
    }
}

// ---------------- 8-phase NT GEMM (round-7 schedule, audited) --------------
// EPI 0: bf16 store. EPI 6: P = exp(s) bf16 store (no sums — see rowsum_k).
template <int BM, int BN, int WR, int WC, int EPI, int GX, int GY, int GZ>
__global__ __launch_bounds__(512, 2) void gemm_8p(
    const bf16* __restrict__ A, int lda, long sAz,
    const bf16* __restrict__ B, int ldb, long sBz,
    void* __restrict__ C0, int ldc, long sCz,
    int nt) {
  constexpr int WM = BM / WR, WN = BN / WC;
  constexpr int FM = WM / 16, FN = WN / 16;
  constexpr int HM = FM / 2, HN = FN / 2;
  constexpr int LA = BM / 128, LB = BN / 128;
  constexpr int NWG = GX * GY * GZ;
  constexpr int CPX = NWG / 8;
  static_assert(WR * WC == 8, "8 waves");
  static_assert(LA == 2 && (LB == 1 || LB == 2), "vmcnt literals");

  __shared__ alignas(16) bf16 As[2][BM * 64];
  __shared__ alignas(16) bf16 Bs[2][BN * 64];

  const int t = threadIdx.x;
  const int lin = blockIdx.x;
  const int wid = (lin & 7) * CPX + (lin >> 3);
  const int bx = wid % GX;
  const int by = (wid / GX) % GY;
  const int bz = wid / (GX * GY);

  const bf16* Aq = A + (size_t)bz * sAz + (size_t)by * BM * lda;
  const bf16* Bq = B + (size_t)bz * sBz + (size_t)bx * BN * ldb;

  const int srow = t >> 3;
  const int sgr  = (t & 7) ^ (srow & 7);

  auto stageA = [&](int buf, int tile, int half) {
    const bf16* src = Aq + (size_t)(half * (BM / 2) + srow) * lda + tile * 64 + sgr * 8;
    bf16* dst = &As[buf][(half * (BM / 2)) * 64] + t * 8;
#pragma unroll
    for (int j = 0; j < LA; ++j)
      gload_lds16(src + (size_t)(j * 64) * lda, dst + j * 4096);
  };
  auto stageB = [&](int buf, int tile, int half) {
    const bf16* src = Bq + (size_t)(half * (BN / 2) + srow) * ldb + tile * 64 + sgr * 8;
    bf16* dst = &Bs[buf][(half * (BN / 2)) * 64] + t * 8;
#pragma unroll
    for (int j = 0; j < LB; ++j)
      gload_lds16(src + (size_t)(j * 64) * ldb, dst + j * 4096);
  };

  const int l = t & 63, w = t >> 6;
  const int wr = w / WC, wc = w % WC;
  const int lr = l & 15, kh = l >> 4;
  const int rs8 = lr & 7;

  bf16x8 af[HM][2], bf_[HN][2];
  auto readA = [&](int buf, int qm) {
#pragma unroll
    for (int i = 0; i < HM; ++i)
#pragma unroll
      for (int h = 0; h < 2; ++h)
        af[i][h] = *(const bf16x8*)(
            &As[buf][(wr * WM + qm * (WM / 2) + i * 16 + lr) * 64 + (((h * 4 + kh) ^ rs8) * 8)]);
  };
  auto readB = [&](int buf, int qn) {
#pragma unroll
    for (int j = 0; j < HN; ++j)
#pragma unroll
      for (int h = 0; h < 2; ++h)
        bf_[j][h] = *(const bf16x8*)(
            &Bs[buf][(wc * WN + qn * (WN / 2) + j * 16 + lr) * 64 + (((h * 4 + kh) ^ rs8) * 8)]);
  };

  f32x4 acc[FM][FN] = {};

#define MFMAQ(QM, QN) { \
  __builtin_amdgcn_s_setprio(1); \
  _Pragma("unroll") for (int ii = 0; ii < HM; ++ii) \
  _Pragma("unroll") for (int jj = 0; jj < HN; ++jj) \
  _Pragma("unroll") for (int h = 0; h < 2; ++h) \
    acc[(QM)*HM + ii][(QN)*HN + jj] = __builtin_amdgcn_mfma_f32_16x16x32_bf16( \
        af[ii][h], bf_[jj][h], acc[(QM)*HM + ii][(QN)*HN + jj], 0, 0, 0); \
  __builtin_amdgcn_s_setprio(0); }
#define WAIT_LB() { if constexpr (LB == 1) VMCNT(1); else VMCNT(2); }

  stageA(0, 0, 0); stageA(0, 0, 1); stageB(0, 0, 0); stageB(0, 0, 1);
  WAIT_LB();
  BAR();

  const int half = nt >> 1;
  for (int i = 0; i < half; ++i) {
    const int t1 = 2 * i + 1, t2 = 2 * i + 2;
    const bool last = (i == half - 1);
    readA(0, 0); readB(0, 0);
    stageA(1, t1, 0);
    BAR();
    MFMAQ(0, 0);
    BAR();
    readA(0, 1);
    stageA(1, t1, 1);
    BAR();
    MFMAQ(1, 0);
    VMCNT(4);
    BAR();
    readB(0, 1);
    stageB(1, t1, 0);
    BAR();
    MFMAQ(1, 1);
    BAR();
    readA(0, 0);
    stageB(1, t1, 1);
    BAR();
    MFMAQ(0, 1);
    WAIT_LB();
    BAR();
    readA(1, 0); readB(1, 0);
    if (!last) stageA(0, t2, 0);
    BAR();
    MFMAQ(0, 0);
    BAR();
    readA(1, 1);
    if (!last) stageA(0, t2, 1);
    BAR();
    MFMAQ(1, 0);
    if (last) { VMCNT(0); } else { VMCNT(4); }
    BAR();
    readB(1, 1);
    if (!last) stageB(0, t2, 0);
    BAR();
    MFMAQ(1, 1);
    BAR();
    readA(1, 0);
    if (!last) stageB(0, t2, 1);
    BAR();
    MFMAQ(0, 1);
    WAIT_LB();
    BAR();
  }
#undef MFMAQ
#undef WAIT_LB

  const int gr0 = by * BM + wr * WM + kh * 4;
  const int gc0 = bx * BN + wc * WN + lr;
  bf16* Cb = (bf16*)C0 + (size_t)bz * sCz;
#pragma unroll
  for (int m = 0; m < FM; ++m)
#pragma unroll
    for (int n = 0; n < FN; ++n) {
      const int c = gc0 + n * 16;
#pragma unroll
      for (int j = 0; j < 4; ++j) {
        const int r = gr0 + m * 16 + j;
        if constexpr (EPI == 6) {
          Cb[(size_t)r * ldc + c] = (bf16)__expf(acc[m][n][j]);
        } else {
          Cb[(size_t)r * ldc + c] = (bf16)acc[m][n][j];
        }
      }
    }
}

// ---------------- launch ----------------
extern "C" void kernel_launch(void* const* d_in, const int* in_sizes, int n_in,
                              void* d_out, int out_size, void* d_ws, size_t ws_size,
                              hipStream_t stream) {
  const float* x     = (const float*)d_in[0];
  const float* gamma = (const float*)d_in[1];
  const float* beta  = (const float*)d_in[2];
  const float* wq = (const float*)d_in[3];
  const float* bq = (const float*)d_in[4];
  const float* wk = (const float*)d_in[5];
  const float* bk = (const float*)d_in[6];
  const float* wv = (const float*)d_in[7];
  const float* bv = (const float*)d_in[8];
  const float* wo = (const float*)d_in[9];
  const float* bo = (const float*)d_in[10];
  float* out = (float*)d_out;
  char* ws = (char*)d_ws;

  float2* stats    = (float2*)(ws + OFF_STATS);
  bf16*   wot      = (bf16*)(ws + OFF_WOT);
  float*  bias_qkv = (float*)(ws + OFF_BIASQ);
  bf16*   wt_qkv   = (bf16*)(ws + OFF_WTQKV);
  bf16*   xn       = (bf16*)(ws + OFF_XN);
  bf16*   qkv      = (bf16*)(ws + OFF_QKV);
  bf16*   vt       = (bf16*)(ws + OFF_VT);
  bf16*   S        = (bf16*)(ws + OFF_S);
  float*  invl     = (float*)(ws + OFF_INVL);
  bf16*   attn     = (bf16*)(ws + OFF_ATTN);
  float2* gn_part  = (float2*)(ws + OFF_GNP);

  const float qscale = 0.04419417382415922f;  // 1/sqrt(512)

  prep_w_k<<<dim3(16, 16, 4), dim3(32, 8), 0, stream>>>(wq, wk, wv, wo, wt_qkv, wot, qscale);
  prep_bias_k<<<6, 256, 0, stream>>>(bq, bk, bv, bias_qkv, qscale);
  gn_part_k<<<1024, 256, 0, stream>>>(x, gn_part);
  gn_finish_k<<<1, 64, 0, stream>>>(gn_part, stats);
  gn_apply_k<<<2048, 256, 0, stream>>>(x, stats, gamma, beta, xn);

  // QKV: [8192,512] @ WT[1536,512]^T -> qkv [8192,1536]  (2-phase, verified)
  gemm_nt<128, 128, 1, 12, 64, 1><<<768, 256, 0, stream>>>(
      xn, 512, 0, wt_qkv, 512, 0, qkv, 1536, 0, 512 / 64, bias_qkv, nullptr);

  // scores+exp: per batch P[4096,4096] = exp(q @ k^T)  (8-phase 256^2)
  gemm_8p<256, 256, 2, 4, 6, 16, 16, 2><<<512, 512, 0, stream>>>(
      qkv, 1536, 4096L * 1536, qkv + 512, 1536, 4096L * 1536,
      S, 4096, 4096L * 4096, 512 / 64);

  // softmax denominators from the bf16-rounded P (consistent with PV operand)
  rowsum_k<<<8192, 256, 0, stream>>>(S, invl);

  transpose_v_k<<<dim3(128, 16, 2), dim3(32, 8), 0, stream>>>(qkv, vt);

  // PV: per batch attn[4096,512] = (P @ VT^T) * invl[row]  (direct bf16 write)
  gemm_nt<128, 64, 5, 8, 32, 2><<<512, 256, 0, stream>>>(
      S, 4096, 4096L * 4096, vt, 4096, 512L * 4096,
      attn, 512, 4096L * 512, 4096 / 64, invl, nullptr);

  // out: [8192,512] = attn @ WOT^T + bo + inputs (fp32)
  gemm_nt<64, 128, 2, 4, 128, 1><<<512, 256, 0, stream>>>(
      attn, 512, 0, wot, 512, 0, out, 512, 0, 512 / 64, bo, x);
}

// Round 10
// 165.075 us; speedup vs baseline: 1.0245x; 1.0245x over previous
//
#include <hip/hip_runtime.h>
#include <math.h>

typedef __bf16 bf16;
typedef __bf16 bf16x8 __attribute__((ext_vector_type(8)));
typedef float  f32x4  __attribute__((ext_vector_type(4)));

#define DEV __device__ __forceinline__
#define VMCNT(n) asm volatile("s_waitcnt vmcnt(" #n ")" ::: "memory")
#define CFENCE  asm volatile("" ::: "memory")
#define BAR()   { CFENCE; __builtin_amdgcn_s_barrier(); CFENCE; }

DEV void gload_lds16(const bf16* g, bf16* l) {
  __builtin_amdgcn_global_load_lds(
      (const __attribute__((address_space(1))) void*)g,
      (__attribute__((address_space(3))) void*)l, 16, 0, 0);
}

// ---------------- workspace layout (bytes) ----------------
#define OFF_STATS 0UL
#define OFF_WOT   1024UL        // 512*512*2 = 524288            -> 525312
#define OFF_BIASQ 525312UL      // 1536*4    = 6144              -> 531456
#define OFF_WTQKV 531456UL      // 1536*512*2 = 1572864          -> 2104320
#define OFF_XN    2104320UL     // 8192*512*2 = 8388608          -> 10492928
#define OFF_QKV   10492928UL    // 8192*1536*2 = 25165824        -> 35658752
#define OFF_VT    35658752UL    // 2*512*4096*2 = 8388608        -> 44047360
#define OFF_S     44047360UL    // 2*4096*4096*2 = 67108864      -> 111156224
#define OFF_INVL  111156224UL   // 8192*4 = 32768                -> 111188992
// overlays (stream-ordered lifetimes):
#define OFF_P0    2104320UL     // f32 2*4096*512*4 = 16777216 (xn dead at PV)
#define OFF_P1    18881536UL    // ends 35658752 == OFF_VT exactly (vt live, no overlap)
#define OFF_ATTN  44047360UL    // overlays S (S dead after PV reads it)
#define OFF_GNP   44047360UL    // gn partials, prep-time only (S written later)

// ---------------- GroupNorm partial stats: 1024 blocks ----------------
__global__ __launch_bounds__(256) void gn_part_k(const float* __restrict__ x,
                                                 float2* __restrict__ part) {
  const int blk = blockIdx.x;
  const int chunk = blk & 15;
  const int bg = blk >> 4;
  const int b = bg >> 5, g = bg & 31;
  const int t = threadIdx.x;
  const int p = chunk * 256 + t;
  const float* xp = x + (size_t)b * (4096 * 512) + (size_t)p * 512 + g * 16;
  float4 v0 = *(const float4*)(xp);
  float4 v1 = *(const float4*)(xp + 4);
  float4 v2 = *(const float4*)(xp + 8);
  float4 v3 = *(const float4*)(xp + 12);
  float s  = v0.x + v0.y + v0.z + v0.w + v1.x + v1.y + v1.z + v1.w
           + v2.x + v2.y + v2.z + v2.w + v3.x + v3.y + v3.z + v3.w;
  float ss = v0.x*v0.x + v0.y*v0.y + v0.z*v0.z + v0.w*v0.w
           + v1.x*v1.x + v1.y*v1.y + v1.z*v1.z + v1.w*v1.w
           + v2.x*v2.x + v2.y*v2.y + v2.z*v2.z + v2.w*v2.w
           + v3.x*v3.x + v3.y*v3.y + v3.z*v3.z + v3.w*v3.w;
#pragma unroll
  for (int off = 32; off; off >>= 1) {
    s  += __shfl_xor(s, off);
    ss += __shfl_xor(ss, off);
  }
  __shared__ float rs[4], rss[4];
  const int w = t >> 6, l = t & 63;
  if (l == 0) { rs[w] = s; rss[w] = ss; }
  __syncthreads();
  if (t == 0)
    part[blk] = make_float2(rs[0] + rs[1] + rs[2] + rs[3],
                            rss[0] + rss[1] + rss[2] + rss[3]);
}

__global__ void gn_finish_k(const float2* __restrict__ part,
                            float2* __restrict__ stats) {
  const int g = threadIdx.x;
  float s = 0.f, ss = 0.f;
#pragma unroll
  for (int c = 0; c < 16; ++c) {
    float2 p = part[g * 16 + c];
    s += p.x; ss += p.y;
  }
  float mean = s * (1.0f / 65536.0f);
  float var  = ss * (1.0f / 65536.0f) - mean * mean;
  stats[g] = make_float2(mean, 1.0f / sqrtf(var + 1e-6f));
}

// ---------------- normalize + bf16 cast ----------------
__global__ __launch_bounds__(256) void gn_apply_k(const float* __restrict__ x,
                                                  const float2* __restrict__ stats,
                                                  const float* __restrict__ gamma,
                                                  const float* __restrict__ beta,
                                                  bf16* __restrict__ xn) {
  size_t i = ((size_t)blockIdx.x * 256 + threadIdx.x) * 8;
  const int c = (int)(i & 511);
  const int b = (int)(i >> 21);
  float2 st = stats[b * 32 + (c >> 4)];
  float4 xa = *(const float4*)(x + i);
  float4 xb = *(const float4*)(x + i + 4);
  float4 ga = *(const float4*)(gamma + c);
  float4 gb = *(const float4*)(gamma + c + 4);
  float4 ba = *(const float4*)(beta + c);
  float4 bb = *(const float4*)(beta + c + 4);
  bf16x8 o;
  o[0] = (bf16)((xa.x - st.x) * st.y * ga.x + ba.x);
  o[1] = (bf16)((xa.y - st.x) * st.y * ga.y + ba.y);
  o[2] = (bf16)((xa.z - st.x) * st.y * ga.z + ba.z);
  o[3] = (bf16)((xa.w - st.x) * st.y * ga.w + ba.w);
  o[4] = (bf16)((xb.x - st.x) * st.y * gb.x + bb.x);
  o[5] = (bf16)((xb.y - st.x) * st.y * gb.y + bb.y);
  o[6] = (bf16)((xb.z - st.x) * st.y * gb.z + bb.z);
  o[7] = (bf16)((xb.w - st.x) * st.y * gb.w + bb.w);
  *(bf16x8*)(xn + i) = o;
}

// ---------------- weight transpose + bf16 convert ----------------
__global__ void prep_w_k(const float* __restrict__ wq, const float* __restrict__ wk,
                         const float* __restrict__ wv, const float* __restrict__ wo,
                         bf16* __restrict__ wt_qkv, bf16* __restrict__ wot, float qscale) {
  const int z = blockIdx.z;
  const float* W = (z == 0) ? wq : (z == 1) ? wk : (z == 2) ? wv : wo;
  bf16* dst = (z < 3) ? (wt_qkv + (size_t)z * 512 * 512) : wot;
  const float s = (z == 0) ? qscale : 1.0f;
  __shared__ float tile[32][33];
  const int i0 = blockIdx.y * 32;
  const int o0 = blockIdx.x * 32;
#pragma unroll
  for (int r = threadIdx.y; r < 32; r += 8)
    tile[r][threadIdx.x] = W[(size_t)(i0 + r) * 512 + o0 + threadIdx.x];
  __syncthreads();
#pragma unroll
  for (int r = threadIdx.y; r < 32; r += 8)
    dst[(size_t)(o0 + r) * 512 + i0 + threadIdx.x] = (bf16)(tile[threadIdx.x][r] * s);
}

__global__ void prep_bias_k(const float* __restrict__ bq, const float* __restrict__ bk,
                            const float* __restrict__ bv, float* __restrict__ bias_qkv,
                            float qscale) {
  int i = blockIdx.x * 256 + threadIdx.x;
  float v = (i < 512) ? bq[i] * qscale : (i < 1024) ? bk[i - 512] : bv[i - 1024];
  bias_qkv[i] = v;
}

// ---------------- V transpose ----------------
__global__ void transpose_v_k(const bf16* __restrict__ qkv, bf16* __restrict__ vt) {
  __shared__ bf16 tile[32][33];
  const int z = blockIdx.z;
  const int n0 = blockIdx.x * 32, d0 = blockIdx.y * 32;
  const bf16* src = qkv + (size_t)z * 4096 * 1536 + 1024;
#pragma unroll
  for (int r = threadIdx.y; r < 32; r += 8)
    tile[r][threadIdx.x] = src[(size_t)(n0 + r) * 1536 + d0 + threadIdx.x];
  __syncthreads();
  bf16* dst = vt + (size_t)z * 512 * 4096;
#pragma unroll
  for (int r = threadIdx.y; r < 32; r += 8)
    dst[(size_t)(d0 + r) * 4096 + n0 + threadIdx.x] = tile[threadIdx.x][r];
}

// ---------------- row sum of P: invl[r] = 1 / sum_c P[r,c] ----------------
// Reads the bf16-ROUNDED P that PV consumes -> normalization exactly
// consistent with the PV operand (round-9 verified: absmax 0.031).
__global__ __launch_bounds__(256) void rowsum_k(const bf16* __restrict__ S,
                                                float* __restrict__ invl) {
  const int r = blockIdx.x;                 // 0..8191
  const bf16* p = S + (size_t)r * 4096 + threadIdx.x * 16;
  bf16x8 u0 = *(const bf16x8*)p;
  bf16x8 u1 = *(const bf16x8*)(p + 8);
  float s = 0.f;
#pragma unroll
  for (int j = 0; j < 8; ++j) s += (float)u0[j] + (float)u1[j];
#pragma unroll
  for (int off = 32; off; off >>= 1) s += __shfl_xor(s, off);
  __shared__ float red[4];
  const int w = threadIdx.x >> 6, l = threadIdx.x & 63;
  if (l == 0) red[w] = s;
  __syncthreads();
  if (threadIdx.x == 0)
    invl[r] = 1.0f / (red[0] + red[1] + red[2] + red[3]);
}

// ---------------- split-K reduce + softmax normalize ----------------
__global__ __launch_bounds__(256) void reduce_pv_k(const float* __restrict__ p0,
                                                   const float* __restrict__ p1,
                                                   const float* __restrict__ invl,
                                                   bf16* __restrict__ attn) {
  size_t i = ((size_t)blockIdx.x * 256 + threadIdx.x) * 8;
  const float il = invl[i >> 9];          // 512 cols per row
  float4 a = *(const float4*)(p0 + i);
  float4 b = *(const float4*)(p0 + i + 4);
  float4 c = *(const float4*)(p1 + i);
  float4 d = *(const float4*)(p1 + i + 4);
  bf16x8 o;
  o[0] = (bf16)((a.x + c.x) * il); o[1] = (bf16)((a.y + c.y) * il);
  o[2] = (bf16)((a.z + c.z) * il); o[3] = (bf16)((a.w + c.w) * il);
  o[4] = (bf16)((b.x + d.x) * il); o[5] = (bf16)((b.y + d.y) * il);
  o[6] = (bf16)((b.z + d.z) * il); o[7] = (bf16)((b.w + d.w) * il);
  *(bf16x8*)(attn + i) = o;
}

// ---------------- NT bf16 MFMA GEMM: BK=64, XOR-swizzled LDS (2-phase) -----
// EPI: 1 +bias bf16; 2 +bias+resid f32
template <int BM, int BN, int EPI, int GX, int GY, int GZ>
__global__ __launch_bounds__(256, 2) void gemm_nt(
    const bf16* __restrict__ A, int lda, long sAz,
    const bf16* __restrict__ B, int ldb, long sBz,
    void* __restrict__ C, int ldc, long sCz,
    int nk,
    const float* __restrict__ bias,
    const float* __restrict__ resid) {
  constexpr int WM = BM / 2, WN = BN / 2;
  constexpr int FM = BM / 32, FN = BN / 32;
  constexpr int NWG = GX * GY * GZ;
  constexpr int CPX = NWG / 8;
  __shared__ alignas(16) bf16 As[2][BM * 64];
  __shared__ alignas(16) bf16 Bs[2][BN * 64];

  const int lin = blockIdx.x;
  const int wid = (lin & 7) * CPX + (lin >> 3);
  const int bx = wid % GX;
  const int by = (wid / GX) % GY;
  const int bz = wid / (GX * GY);

  const int t = threadIdx.x;
  const bf16* Aq = A + (size_t)bz * sAz + (size_t)by * BM * lda;
  const bf16* Bq = B + (size_t)bz * sBz + (size_t)bx * BN * ldb;

  const int srow = t >> 3;
  const int sg   = (t & 7) ^ (srow & 7);

  auto stage = [&](int buf, int kt) {
    const int k0 = kt * 64 + sg * 8;
#pragma unroll
    for (int i = 0; i < BM / 32; ++i)
      gload_lds16(Aq + (size_t)(i * 32 + srow) * lda + k0, &As[buf][i * 2048 + t * 8]);
#pragma unroll
    for (int i = 0; i < BN / 32; ++i)
      gload_lds16(Bq + (size_t)(i * 32 + srow) * ldb + k0, &Bs[buf][i * 2048 + t * 8]);
  };

  const int l = t & 63, w = t >> 6;
  const int wr = w >> 1, wc = w & 1;
  const int lr = l & 15, kh = l >> 4;
  const int rs = lr & 7;

  f32x4 acc[FM][FN] = {};

  stage(0, 0);
  for (int kt = 0; kt < nk; ++kt) {
    __syncthreads();
    if (kt + 1 < nk) stage((kt + 1) & 1, kt + 1);
    const int buf = kt & 1;
    bf16x8 a[2][FM], b[2][FN];
#pragma unroll
    for (int h = 0; h < 2; ++h) {
      const int g = ((h * 4 + kh) ^ rs) * 8;
#pragma unroll
      for (int m = 0; m < FM; ++m)
        a[h][m] = *(const bf16x8*)(&As[buf][(wr * WM + m * 16 + lr) * 64 + g]);
#pragma unroll
      for (int n = 0; n < FN; ++n)
        b[h][n] = *(const bf16x8*)(&Bs[buf][(wc * WN + n * 16 + lr) * 64 + g]);
    }
#pragma unroll
    for (int h = 0; h < 2; ++h)
#pragma unroll
      for (int m = 0; m < FM; ++m)
#pragma unroll
        for (int n = 0; n < FN; ++n)
          acc[m][n] = __builtin_amdgcn_mfma_f32_16x16x32_bf16(a[h][m], b[h][n], acc[m][n], 0, 0, 0);
  }

  const int gr0 = by * BM + wr * WM + kh * 4;
  const int gc0 = bx * BN + wc * WN + lr;
#pragma unroll
  for (int m = 0; m < FM; ++m)
#pragma unroll
    for (int n = 0; n < FN; ++n) {
      const int c = gc0 + n * 16;
      float bv = bias[c];
#pragma unroll
      for (int j = 0; j < 4; ++j) {
        const int r = gr0 + m * 16 + j;
        float val = acc[m][n][j] + bv;
        if constexpr (EPI == 2) {
          float* Cf = (float*)C + (size_t)bz * sCz;
          Cf[(size_t)r * ldc + c] = val + resid[(size_t)r * ldc + c];
        } else {
          bf16* Cb = (bf16*)C + (size_t)bz * sCz;
          Cb[(size_t)r * ldc + c] = (bf16)val;
        }
      }
    }
}

// ---------------- 8-phase NT GEMM (round-7 schedule, audited) --------------
// EPI 6: P = exp(s) bf16 store. EPI 3: f32 split-K partial to (ks ? C1 : C0).
template <int BM, int BN, int WR, int WC, int EPI, int GX, int GY, int GZ, int KS>
__global__ __launch_bounds__(512, 2) void gemm_8p(
    const bf16* __restrict__ A, int lda, long sAz,
    const bf16* __restrict__ B, int ldb, long sBz,
    void* __restrict__ C0, void* __restrict__ C1, int ldc, long sCz,
    int nt) {
  constexpr int WM = BM / WR, WN = BN / WC;
  constexpr int FM = WM / 16, FN = WN / 16;
  constexpr int HM = FM / 2, HN = FN / 2;
  constexpr int LA = BM / 128, LB = BN / 128;
  constexpr int NWG = GX * KS * GY * GZ;
  constexpr int CPX = NWG / 8;
  static_assert(WR * WC == 8, "8 waves");
  static_assert(LA == 2 && (LB == 1 || LB == 2), "vmcnt literals");

  __shared__ alignas(16) bf16 As[2][BM * 64];
  __shared__ alignas(16) bf16 Bs[2][BN * 64];

  const int t = threadIdx.x;
  const int lin = blockIdx.x;
  const int wid = (lin & 7) * CPX + (lin >> 3);
  const int bx = wid % GX;
  const int ks = (wid / GX) % KS;
  const int by = (wid / (GX * KS)) % GY;
  const int bz = wid / (GX * KS * GY);

  const long kOff = (long)ks * nt * 64;
  const bf16* Aq = A + (size_t)bz * sAz + (size_t)by * BM * lda + kOff;
  const bf16* Bq = B + (size_t)bz * sBz + (size_t)bx * BN * ldb + kOff;

  const int srow = t >> 3;
  const int sgr  = (t & 7) ^ (srow & 7);

  auto stageA = [&](int buf, int tile, int half) {
    const bf16* src = Aq + (size_t)(half * (BM / 2) + srow) * lda + tile * 64 + sgr * 8;
    bf16* dst = &As[buf][(half * (BM / 2)) * 64] + t * 8;
#pragma unroll
    for (int j = 0; j < LA; ++j)
      gload_lds16(src + (size_t)(j * 64) * lda, dst + j * 4096);
  };
  auto stageB = [&](int buf, int tile, int half) {
    const bf16* src = Bq + (size_t)(half * (BN / 2) + srow) * ldb + tile * 64 + sgr * 8;
    bf16* dst = &Bs[buf][(half * (BN / 2)) * 64] + t * 8;
#pragma unroll
    for (int j = 0; j < LB; ++j)
      gload_lds16(src + (size_t)(j * 64) * ldb, dst + j * 4096);
  };

  const int l = t & 63, w = t >> 6;
  const int wr = w / WC, wc = w % WC;
  const int lr = l & 15, kh = l >> 4;
  const int rs8 = lr & 7;

  bf16x8 af[HM][2], bf_[HN][2];
  auto readA = [&](int buf, int qm) {
#pragma unroll
    for (int i = 0; i < HM; ++i)
#pragma unroll
      for (int h = 0; h < 2; ++h)
        af[i][h] = *(const bf16x8*)(
            &As[buf][(wr * WM + qm * (WM / 2) + i * 16 + lr) * 64 + (((h * 4 + kh) ^ rs8) * 8)]);
  };
  auto readB = [&](int buf, int qn) {
#pragma unroll
    for (int j = 0; j < HN; ++j)
#pragma unroll
      for (int h = 0; h < 2; ++h)
        bf_[j][h] = *(const bf16x8*)(
            &Bs[buf][(wc * WN + qn * (WN / 2) + j * 16 + lr) * 64 + (((h * 4 + kh) ^ rs8) * 8)]);
  };

  f32x4 acc[FM][FN] = {};

#define MFMAQ(QM, QN) { \
  __builtin_amdgcn_s_setprio(1); \
  _Pragma("unroll") for (int ii = 0; ii < HM; ++ii) \
  _Pragma("unroll") for (int jj = 0; jj < HN; ++jj) \
  _Pragma("unroll") for (int h = 0; h < 2; ++h) \
    acc[(QM)*HM + ii][(QN)*HN + jj] = __builtin_amdgcn_mfma_f32_16x16x32_bf16( \
        af[ii][h], bf_[jj][h], acc[(QM)*HM + ii][(QN)*HN + jj], 0, 0, 0); \
  __builtin_amdgcn_s_setprio(0); }
#define WAIT_LB() { if constexpr (LB == 1) VMCNT(1); else VMCNT(2); }

  stageA(0, 0, 0); stageA(0, 0, 1); stageB(0, 0, 0); stageB(0, 0, 1);
  WAIT_LB();
  BAR();

  const int half = nt >> 1;
  for (int i = 0; i < half; ++i) {
    const int t1 = 2 * i + 1, t2 = 2 * i + 2;
    const bool last = (i == half - 1);
    readA(0, 0); readB(0, 0);
    stageA(1, t1, 0);
    BAR();
    MFMAQ(0, 0);
    BAR();
    readA(0, 1);
    stageA(1, t1, 1);
    BAR();
    MFMAQ(1, 0);
    VMCNT(4);
    BAR();
    readB(0, 1);
    stageB(1, t1, 0);
    BAR();
    MFMAQ(1, 1);
    BAR();
    readA(0, 0);
    stageB(1, t1, 1);
    BAR();
    MFMAQ(0, 1);
    WAIT_LB();
    BAR();
    readA(1, 0); readB(1, 0);
    if (!last) stageA(0, t2, 0);
    BAR();
    MFMAQ(0, 0);
    BAR();
    readA(1, 1);
    if (!last) stageA(0, t2, 1);
    BAR();
    MFMAQ(1, 0);
    if (last) { VMCNT(0); } else { VMCNT(4); }
    BAR();
    readB(1, 1);
    if (!last) stageB(0, t2, 0);
    BAR();
    MFMAQ(1, 1);
    BAR();
    readA(1, 0);
    if (!last) stageB(0, t2, 1);
    BAR();
    MFMAQ(0, 1);
    WAIT_LB();
    BAR();
  }
#undef MFMAQ
#undef WAIT_LB

  const int gr0 = by * BM + wr * WM + kh * 4;
  const int gc0 = bx * BN + wc * WN + lr;
#pragma unroll
  for (int m = 0; m < FM; ++m)
#pragma unroll
    for (int n = 0; n < FN; ++n) {
      const int c = gc0 + n * 16;
#pragma unroll
      for (int j = 0; j < 4; ++j) {
        const int r = gr0 + m * 16 + j;
        if constexpr (EPI == 6) {
          bf16* Cb = (bf16*)C0 + (size_t)bz * sCz;
          Cb[(size_t)r * ldc + c] = (bf16)__expf(acc[m][n][j]);
        } else {  // EPI == 3: f32 split-K partial
          float* Cf = (float*)(ks ? C1 : C0) + (size_t)bz * sCz;
          Cf[(size_t)r * ldc + c] = acc[m][n][j];
        }
      }
    }
}

// ---------------- launch ----------------
extern "C" void kernel_launch(void* const* d_in, const int* in_sizes, int n_in,
                              void* d_out, int out_size, void* d_ws, size_t ws_size,
                              hipStream_t stream) {
  const float* x     = (const float*)d_in[0];
  const float* gamma = (const float*)d_in[1];
  const float* beta  = (const float*)d_in[2];
  const float* wq = (const float*)d_in[3];
  const float* bq = (const float*)d_in[4];
  const float* wk = (const float*)d_in[5];
  const float* bk = (const float*)d_in[6];
  const float* wv = (const float*)d_in[7];
  const float* bv = (const float*)d_in[8];
  const float* wo = (const float*)d_in[9];
  const float* bo = (const float*)d_in[10];
  float* out = (float*)d_out;
  char* ws = (char*)d_ws;

  float2* stats    = (float2*)(ws + OFF_STATS);
  bf16*   wot      = (bf16*)(ws + OFF_WOT);
  float*  bias_qkv = (float*)(ws + OFF_BIASQ);
  bf16*   wt_qkv   = (bf16*)(ws + OFF_WTQKV);
  bf16*   xn       = (bf16*)(ws + OFF_XN);
  bf16*   qkv      = (bf16*)(ws + OFF_QKV);
  bf16*   vt       = (bf16*)(ws + OFF_VT);
  bf16*   S        = (bf16*)(ws + OFF_S);
  float*  invl     = (float*)(ws + OFF_INVL);
  float*  p0       = (float*)(ws + OFF_P0);
  float*  p1       = (float*)(ws + OFF_P1);
  bf16*   attn     = (bf16*)(ws + OFF_ATTN);
  float2* gn_part  = (float2*)(ws + OFF_GNP);

  const float qscale = 0.04419417382415922f;  // 1/sqrt(512)

  prep_w_k<<<dim3(16, 16, 4), dim3(32, 8), 0, stream>>>(wq, wk, wv, wo, wt_qkv, wot, qscale);
  prep_bias_k<<<6, 256, 0, stream>>>(bq, bk, bv, bias_qkv, qscale);
  gn_part_k<<<1024, 256, 0, stream>>>(x, gn_part);
  gn_finish_k<<<1, 64, 0, stream>>>(gn_part, stats);
  gn_apply_k<<<2048, 256, 0, stream>>>(x, stats, gamma, beta, xn);

  // QKV: [8192,512] @ WT[1536,512]^T -> qkv [8192,1536]  (2-phase, verified)
  gemm_nt<128, 128, 1, 12, 64, 1><<<768, 256, 0, stream>>>(
      xn, 512, 0, wt_qkv, 512, 0, qkv, 1536, 0, 512 / 64, bias_qkv, nullptr);

  // scores+exp: per batch P[4096,4096] = exp(q @ k^T)  (8-phase 256^2)
  gemm_8p<256, 256, 2, 4, 6, 16, 16, 2, 1><<<512, 512, 0, stream>>>(
      qkv, 1536, 4096L * 1536, qkv + 512, 1536, 4096L * 1536,
      S, nullptr, 4096, 4096L * 4096, 512 / 64);

  // softmax denominators from the bf16-rounded P (consistent with PV operand)
  rowsum_k<<<8192, 256, 0, stream>>>(S, invl);

  transpose_v_k<<<dim3(128, 16, 2), dim3(32, 8), 0, stream>>>(qkv, vt);

  // PV: per batch [4096,512] = P @ VT^T  (8-phase 256x128, split-K=2 -> f32)
  gemm_8p<256, 128, 4, 2, 3, 4, 16, 2, 2><<<256, 512, 0, stream>>>(
      S, 4096, 4096L * 4096, vt, 4096, 512L * 4096,
      p0, p1, 512, 4096L * 512, 2048 / 64);

  // reduce + normalize: attn = bf16((p0+p1) * inv_l[row])
  reduce_pv_k<<<2048, 256, 0, stream>>>(p0, p1, invl, attn);

  // out: [8192,512] = attn @ WOT^T + bo + inputs (fp32)
  gemm_nt<64, 128, 2, 4, 128, 1><<<512, 256, 0, stream>>>(
      attn, 512, 0, wot, 512, 0, out, 512, 0, 512 / 64, bo, x);
}

// Round 11
// 163.823 us; speedup vs baseline: 1.0323x; 1.0076x over previous
//
#include <hip/hip_runtime.h>
#include <math.h>

typedef __bf16 bf16;
typedef __bf16 bf16x8 __attribute__((ext_vector_type(8)));
typedef float  f32x4  __attribute__((ext_vector_type(4)));

#define DEV __device__ __forceinline__
#define VMCNT(n) asm volatile("s_waitcnt vmcnt(" #n ")" ::: "memory")
#define CFENCE  asm volatile("" ::: "memory")
#define BAR()   { CFENCE; __builtin_amdgcn_s_barrier(); CFENCE; }

DEV void gload_lds16(const bf16* g, bf16* l) {
  __builtin_amdgcn_global_load_lds(
      (const __attribute__((address_space(1))) void*)g,
      (__attribute__((address_space(3))) void*)l, 16, 0, 0);
}

// ---------------- workspace layout (bytes) ----------------
#define OFF_STATS 0UL
#define OFF_WOT   1024UL        // 512*512*2 = 524288            -> 525312
#define OFF_BIASQ 525312UL      // 1536*4    = 6144              -> 531456
#define OFF_WTQKV 531456UL      // 1536*512*2 = 1572864          -> 2104320
#define OFF_XN    2104320UL     // 8192*512*2 = 8388608          -> 10492928
#define OFF_QKV   10492928UL    // 8192*1536*2 = 25165824        -> 35658752
#define OFF_VT    35658752UL    // 2*512*4096*2 = 8388608        -> 44047360
#define OFF_S     44047360UL    // 2*4096*4096*2 = 67108864      -> 111156224
#define OFF_INVL  111156224UL   // 8192*4 = 32768                -> 111188992
// overlays (stream-ordered lifetimes):
#define OFF_P0    2104320UL     // f32 2*4096*512*4 = 16777216 (xn dead at PV)
#define OFF_P1    18881536UL    // ends 35658752 == OFF_VT exactly (vt live, no overlap)
#define OFF_ATTN  44047360UL    // overlays S (S dead after PV reads it)
#define OFF_GNP   44047360UL    // gn partials, prep-time only (S written later)

// ---------------- GroupNorm partial stats: 1024 blocks ----------------
__global__ __launch_bounds__(256) void gn_part_k(const float* __restrict__ x,
                                                 float2* __restrict__ part) {
  const int blk = blockIdx.x;
  const int chunk = blk & 15;
  const int bg = blk >> 4;
  const int b = bg >> 5, g = bg & 31;
  const int t = threadIdx.x;
  const int p = chunk * 256 + t;
  const float* xp = x + (size_t)b * (4096 * 512) + (size_t)p * 512 + g * 16;
  float4 v0 = *(const float4*)(xp);
  float4 v1 = *(const float4*)(xp + 4);
  float4 v2 = *(const float4*)(xp + 8);
  float4 v3 = *(const float4*)(xp + 12);
  float s  = v0.x + v0.y + v0.z + v0.w + v1.x + v1.y + v1.z + v1.w
           + v2.x + v2.y + v2.z + v2.w + v3.x + v3.y + v3.z + v3.w;
  float ss = v0.x*v0.x + v0.y*v0.y + v0.z*v0.z + v0.w*v0.w
           + v1.x*v1.x + v1.y*v1.y + v1.z*v1.z + v1.w*v1.w
           + v2.x*v2.x + v2.y*v2.y + v2.z*v2.z + v2.w*v2.w
           + v3.x*v3.x + v3.y*v3.y + v3.z*v3.z + v3.w*v3.w;
#pragma unroll
  for (int off = 32; off; off >>= 1) {
    s  += __shfl_xor(s, off);
    ss += __shfl_xor(ss, off);
  }
  __shared__ float rs[4], rss[4];
  const int w = t >> 6, l = t & 63;
  if (l == 0) { rs[w] = s; rss[w] = ss; }
  __syncthreads();
  if (t == 0)
    part[blk] = make_float2(rs[0] + rs[1] + rs[2] + rs[3],
                            rss[0] + rss[1] + rss[2] + rss[3]);
}

__global__ void gn_finish_k(const float2* __restrict__ part,
                            float2* __restrict__ stats) {
  const int g = threadIdx.x;
  float s = 0.f, ss = 0.f;
#pragma unroll
  for (int c = 0; c < 16; ++c) {
    float2 p = part[g * 16 + c];
    s += p.x; ss += p.y;
  }
  float mean = s * (1.0f / 65536.0f);
  float var  = ss * (1.0f / 65536.0f) - mean * mean;
  stats[g] = make_float2(mean, 1.0f / sqrtf(var + 1e-6f));
}

// ---------------- normalize + bf16 cast ----------------
__global__ __launch_bounds__(256) void gn_apply_k(const float* __restrict__ x,
                                                  const float2* __restrict__ stats,
                                                  const float* __restrict__ gamma,
                                                  const float* __restrict__ beta,
                                                  bf16* __restrict__ xn) {
  size_t i = ((size_t)blockIdx.x * 256 + threadIdx.x) * 8;
  const int c = (int)(i & 511);
  const int b = (int)(i >> 21);
  float2 st = stats[b * 32 + (c >> 4)];
  float4 xa = *(const float4*)(x + i);
  float4 xb = *(const float4*)(x + i + 4);
  float4 ga = *(const float4*)(gamma + c);
  float4 gb = *(const float4*)(gamma + c + 4);
  float4 ba = *(const float4*)(beta + c);
  float4 bb = *(const float4*)(beta + c + 4);
  bf16x8 o;
  o[0] = (bf16)((xa.x - st.x) * st.y * ga.x + ba.x);
  o[1] = (bf16)((xa.y - st.x) * st.y * ga.y + ba.y);
  o[2] = (bf16)((xa.z - st.x) * st.y * ga.z + ba.z);
  o[3] = (bf16)((xa.w - st.x) * st.y * ga.w + ba.w);
  o[4] = (bf16)((xb.x - st.x) * st.y * gb.x + bb.x);
  o[5] = (bf16)((xb.y - st.x) * st.y * gb.y + bb.y);
  o[6] = (bf16)((xb.z - st.x) * st.y * gb.z + bb.z);
  o[7] = (bf16)((xb.w - st.x) * st.y * gb.w + bb.w);
  *(bf16x8*)(xn + i) = o;
}

// ---------------- weight transpose + bf16 convert ----------------
__global__ void prep_w_k(const float* __restrict__ wq, const float* __restrict__ wk,
                         const float* __restrict__ wv, const float* __restrict__ wo,
                         bf16* __restrict__ wt_qkv, bf16* __restrict__ wot, float qscale) {
  const int z = blockIdx.z;
  const float* W = (z == 0) ? wq : (z == 1) ? wk : (z == 2) ? wv : wo;
  bf16* dst = (z < 3) ? (wt_qkv + (size_t)z * 512 * 512) : wot;
  const float s = (z == 0) ? qscale : 1.0f;
  __shared__ float tile[32][33];
  const int i0 = blockIdx.y * 32;
  const int o0 = blockIdx.x * 32;
#pragma unroll
  for (int r = threadIdx.y; r < 32; r += 8)
    tile[r][threadIdx.x] = W[(size_t)(i0 + r) * 512 + o0 + threadIdx.x];
  __syncthreads();
#pragma unroll
  for (int r = threadIdx.y; r < 32; r += 8)
    dst[(size_t)(o0 + r) * 512 + i0 + threadIdx.x] = (bf16)(tile[threadIdx.x][r] * s);
}

__global__ void prep_bias_k(const float* __restrict__ bq, const float* __restrict__ bk,
                            const float* __restrict__ bv, float* __restrict__ bias_qkv,
                            float qscale) {
  int i = blockIdx.x * 256 + threadIdx.x;
  float v = (i < 512) ? bq[i] * qscale : (i < 1024) ? bk[i - 512] : bv[i - 1024];
  bias_qkv[i] = v;
}

// ---------------- V transpose ----------------
__global__ void transpose_v_k(const bf16* __restrict__ qkv, bf16* __restrict__ vt) {
  __shared__ bf16 tile[32][33];
  const int z = blockIdx.z;
  const int n0 = blockIdx.x * 32, d0 = blockIdx.y * 32;
  const bf16* src = qkv + (size_t)z * 4096 * 1536 + 1024;
#pragma unroll
  for (int r = threadIdx.y; r < 32; r += 8)
    tile[r][threadIdx.x] = src[(size_t)(n0 + r) * 1536 + d0 + threadIdx.x];
  __syncthreads();
  bf16* dst = vt + (size_t)z * 512 * 4096;
#pragma unroll
  for (int r = threadIdx.y; r < 32; r += 8)
    dst[(size_t)(d0 + r) * 4096 + n0 + threadIdx.x] = tile[threadIdx.x][r];
}

// ---------------- row sum of P: invl[r] = 1 / sum_c P[r,c] ----------------
__global__ __launch_bounds__(256) void rowsum_k(const bf16* __restrict__ S,
                                                float* __restrict__ invl) {
  const int r = blockIdx.x;                 // 0..8191
  const bf16* p = S + (size_t)r * 4096 + threadIdx.x * 16;
  bf16x8 u0 = *(const bf16x8*)p;
  bf16x8 u1 = *(const bf16x8*)(p + 8);
  float s = 0.f;
#pragma unroll
  for (int j = 0; j < 8; ++j) s += (float)u0[j] + (float)u1[j];
#pragma unroll
  for (int off = 32; off; off >>= 1) s += __shfl_xor(s, off);
  __shared__ float red[4];
  const int w = threadIdx.x >> 6, l = threadIdx.x & 63;
  if (l == 0) red[w] = s;
  __syncthreads();
  if (threadIdx.x == 0)
    invl[r] = 1.0f / (red[0] + red[1] + red[2] + red[3]);
}

// ---------------- split-K reduce + softmax normalize ----------------
__global__ __launch_bounds__(256) void reduce_pv_k(const float* __restrict__ p0,
                                                   const float* __restrict__ p1,
                                                   const float* __restrict__ invl,
                                                   bf16* __restrict__ attn) {
  size_t i = ((size_t)blockIdx.x * 256 + threadIdx.x) * 8;
  const float il = invl[i >> 9];          // 512 cols per row
  float4 a = *(const float4*)(p0 + i);
  float4 b = *(const float4*)(p0 + i + 4);
  float4 c = *(const float4*)(p1 + i);
  float4 d = *(const float4*)(p1 + i + 4);
  bf16x8 o;
  o[0] = (bf16)((a.x + c.x) * il); o[1] = (bf16)((a.y + c.y) * il);
  o[2] = (bf16)((a.z + c.z) * il); o[3] = (bf16)((a.w + c.w) * il);
  o[4] = (bf16)((b.x + d.x) * il); o[5] = (bf16)((b.y + d.y) * il);
  o[6] = (bf16)((b.z + d.z) * il); o[7] = (bf16)((b.w + d.w) * il);
  *(bf16x8*)(attn + i) = o;
}

// ---------------- NT bf16 MFMA GEMM: BK=64, XOR-swizzled LDS (2-phase) -----
// EPI: 1 +bias bf16; 2 +bias+resid f32
template <int BM, int BN, int EPI, int GX, int GY, int GZ>
__global__ __launch_bounds__(256, 2) void gemm_nt(
    const bf16* __restrict__ A, int lda, long sAz,
    const bf16* __restrict__ B, int ldb, long sBz,
    void* __restrict__ C, int ldc, long sCz,
    int nk,
    const float* __restrict__ bias,
    const float* __restrict__ resid) {
  constexpr int WM = BM / 2, WN = BN / 2;
  constexpr int FM = BM / 32, FN = BN / 32;
  constexpr int NWG = GX * GY * GZ;
  constexpr int CPX = NWG / 8;
  __shared__ alignas(16) bf16 As[2][BM * 64];
  __shared__ alignas(16) bf16 Bs[2][BN * 64];

  const int lin = blockIdx.x;
  const int wid = (lin & 7) * CPX + (lin >> 3);
  const int bx = wid % GX;
  const int by = (wid / GX) % GY;
  const int bz = wid / (GX * GY);

  const int t = threadIdx.x;
  const bf16* Aq = A + (size_t)bz * sAz + (size_t)by * BM * lda;
  const bf16* Bq = B + (size_t)bz * sBz + (size_t)bx * BN * ldb;

  const int srow = t >> 3;
  const int sg   = (t & 7) ^ (srow & 7);

  auto stage = [&](int buf, int kt) {
    const int k0 = kt * 64 + sg * 8;
#pragma unroll
    for (int i = 0; i < BM / 32; ++i)
      gload_lds16(Aq + (size_t)(i * 32 + srow) * lda + k0, &As[buf][i * 2048 + t * 8]);
#pragma unroll
    for (int i = 0; i < BN / 32; ++i)
      gload_lds16(Bq + (size_t)(i * 32 + srow) * ldb + k0, &Bs[buf][i * 2048 + t * 8]);
  };

  const int l = t & 63, w = t >> 6;
  const int wr = w >> 1, wc = w & 1;
  const int lr = l & 15, kh = l >> 4;
  const int rs = lr & 7;

  f32x4 acc[FM][FN] = {};

  stage(0, 0);
  for (int kt = 0; kt < nk; ++kt) {
    __syncthreads();
    if (kt + 1 < nk) stage((kt + 1) & 1, kt + 1);
    const int buf = kt & 1;
    bf16x8 a[2][FM], b[2][FN];
#pragma unroll
    for (int h = 0; h < 2; ++h) {
      const int g = ((h * 4 + kh) ^ rs) * 8;
#pragma unroll
      for (int m = 0; m < FM; ++m)
        a[h][m] = *(const bf16x8*)(&As[buf][(wr * WM + m * 16 + lr) * 64 + g]);
#pragma unroll
      for (int n = 0; n < FN; ++n)
        b[h][n] = *(const bf16x8*)(&Bs[buf][(wc * WN + n * 16 + lr) * 64 + g]);
    }
#pragma unroll
    for (int h = 0; h < 2; ++h)
#pragma unroll
      for (int m = 0; m < FM; ++m)
#pragma unroll
        for (int n = 0; n < FN; ++n)
          acc[m][n] = __builtin_amdgcn_mfma_f32_16x16x32_bf16(a[h][m], b[h][n], acc[m][n], 0, 0, 0);
  }

  const int gr0 = by * BM + wr * WM + kh * 4;
  const int gc0 = bx * BN + wc * WN + lr;
#pragma unroll
  for (int m = 0; m < FM; ++m)
#pragma unroll
    for (int n = 0; n < FN; ++n) {
      const int c = gc0 + n * 16;
      float bv = bias[c];
#pragma unroll
      for (int j = 0; j < 4; ++j) {
        const int r = gr0 + m * 16 + j;
        float val = acc[m][n][j] + bv;
        if constexpr (EPI == 2) {
          float* Cf = (float*)C + (size_t)bz * sCz;
          Cf[(size_t)r * ldc + c] = val + resid[(size_t)r * ldc + c];
        } else {
          bf16* Cb = (bf16*)C + (size_t)bz * sCz;
          Cb[(size_t)r * ldc + c] = (bf16)val;
        }
      }
    }
}

// ---------------- 8-phase NT GEMM with chained output tiles ----------------
// EPI 6: P = exp(s) bf16 store. EPI 3: f32 split-K partial to (ks ? C1 : C0).
// REPS output row-tiles per block, chained: at the last iteration of rep r,
// the P5-P8 staging slots (idle under `if (!last)`) stage rep r+1's K-tile 0
// into buf0 -- reproducing the prologue state exactly (P8's WAIT_LB leaves
// A0,A1,B0 landed + B1 in flight; same vmcnt invariant, 8 loads per iter).
// Rep r's epilogue then overlaps rep r+1's first-tile loads. REPS=1 reduces
// to the round-7..10 audited schedule token-for-token.
template <int BM, int BN, int WR, int WC, int EPI, int GX, int GY, int GZ,
          int KS, int REPS>
__global__ __launch_bounds__(512, 2) void gemm_8p(
    const bf16* __restrict__ A, int lda, long sAz,
    const bf16* __restrict__ B, int ldb, long sBz,
    void* __restrict__ C0, void* __restrict__ C1, int ldc, long sCz,
    int nt) {
  constexpr int WM = BM / WR, WN = BN / WC;
  constexpr int FM = WM / 16, FN = WN / 16;
  constexpr int HM = FM / 2, HN = FN / 2;
  constexpr int LA = BM / 128, LB = BN / 128;
  constexpr int NWG = GX * KS * GY * GZ;
  constexpr int CPX = NWG / 8;
  static_assert(WR * WC == 8, "8 waves");
  static_assert(LA == 2 && (LB == 1 || LB == 2), "vmcnt literals");

  __shared__ alignas(16) bf16 As[2][BM * 64];
  __shared__ alignas(16) bf16 Bs[2][BN * 64];

  const int t = threadIdx.x;
  const int lin = blockIdx.x;
  const int wid = (lin & 7) * CPX + (lin >> 3);
  const int bx = wid % GX;
  const int ks = (wid / GX) % KS;
  const int byg = (wid / (GX * KS)) % GY;     // row-tile GROUP (REPS tiles)
  const int bz = wid / (GX * KS * GY);

  const long kOff = (long)ks * nt * 64;
  const bf16* Bq = B + (size_t)bz * sBz + (size_t)bx * BN * ldb + kOff;
  auto abase = [&](int rep) {
    return A + (size_t)bz * sAz + (size_t)(byg * REPS + rep) * BM * lda + kOff;
  };

  const int srow = t >> 3;
  const int sgr  = (t & 7) ^ (srow & 7);

  auto stageA = [&](const bf16* Ab, int buf, int tile, int half) {
    const bf16* src = Ab + (size_t)(half * (BM / 2) + srow) * lda + tile * 64 + sgr * 8;
    bf16* dst = &As[buf][(half * (BM / 2)) * 64] + t * 8;
#pragma unroll
    for (int j = 0; j < LA; ++j)
      gload_lds16(src + (size_t)(j * 64) * lda, dst + j * 4096);
  };
  auto stageB = [&](int buf, int tile, int half) {
    const bf16* src = Bq + (size_t)(half * (BN / 2) + srow) * ldb + tile * 64 + sgr * 8;
    bf16* dst = &Bs[buf][(half * (BN / 2)) * 64] + t * 8;
#pragma unroll
    for (int j = 0; j < LB; ++j)
      gload_lds16(src + (size_t)(j * 64) * ldb, dst + j * 4096);
  };

  const int l = t & 63, w = t >> 6;
  const int wr = w / WC, wc = w % WC;
  const int lr = l & 15, kh = l >> 4;
  const int rs8 = lr & 7;

  bf16x8 af[HM][2], bf_[HN][2];
  auto readA = [&](int buf, int qm) {
#pragma unroll
    for (int i = 0; i < HM; ++i)
#pragma unroll
      for (int h = 0; h < 2; ++h)
        af[i][h] = *(const bf16x8*)(
            &As[buf][(wr * WM + qm * (WM / 2) + i * 16 + lr) * 64 + (((h * 4 + kh) ^ rs8) * 8)]);
  };
  auto readB = [&](int buf, int qn) {
#pragma unroll
    for (int j = 0; j < HN; ++j)
#pragma unroll
      for (int h = 0; h < 2; ++h)
        bf_[j][h] = *(const bf16x8*)(
            &Bs[buf][(wc * WN + qn * (WN / 2) + j * 16 + lr) * 64 + (((h * 4 + kh) ^ rs8) * 8)]);
  };

  f32x4 acc[FM][FN] = {};

#define MFMAQ(QM, QN) { \
  __builtin_amdgcn_s_setprio(1); \
  _Pragma("unroll") for (int ii = 0; ii < HM; ++ii) \
  _Pragma("unroll") for (int jj = 0; jj < HN; ++jj) \
  _Pragma("unroll") for (int h = 0; h < 2; ++h) \
    acc[(QM)*HM + ii][(QN)*HN + jj] = __builtin_amdgcn_mfma_f32_16x16x32_bf16( \
        af[ii][h], bf_[jj][h], acc[(QM)*HM + ii][(QN)*HN + jj], 0, 0, 0); \
  __builtin_amdgcn_s_setprio(0); }
#define WAIT_LB() { if constexpr (LB == 1) VMCNT(1); else VMCNT(2); }

  // prologue: rep 0, tile 0 -> buf0
  {
    const bf16* A0 = abase(0);
    stageA(A0, 0, 0, 0); stageA(A0, 0, 0, 1); stageB(0, 0, 0); stageB(0, 0, 1);
  }
  WAIT_LB();
  BAR();

  const int half = nt >> 1;
#pragma unroll
  for (int rep = 0; rep < REPS; ++rep) {
    const bf16* Ar = abase(rep);
    const bf16* An = abase(rep + 1 < REPS ? rep + 1 : rep);   // guarded use
    for (int i = 0; i < half; ++i) {
      const int t1 = 2 * i + 1, t2 = 2 * i + 2;
      const bool lastI = (i == half - 1);
      const bool lastAll = lastI && (rep == REPS - 1);
      // ---- P1 ----
      readA(0, 0); readB(0, 0);
      stageA(Ar, 1, t1, 0);
      BAR();
      MFMAQ(0, 0);
      BAR();
      // ---- P2 ----
      readA(0, 1);
      stageA(Ar, 1, t1, 1);
      BAR();
      MFMAQ(1, 0);
      VMCNT(4);
      BAR();
      // ---- P3 ----
      readB(0, 1);
      stageB(1, t1, 0);
      BAR();
      MFMAQ(1, 1);
      BAR();
      // ---- P4 ----
      readA(0, 0);
      stageB(1, t1, 1);
      BAR();
      MFMAQ(0, 1);
      WAIT_LB();
      BAR();
      // ---- P5 ----
      readA(1, 0); readB(1, 0);
      if (!lastI) stageA(Ar, 0, t2, 0);
      else if (!lastAll) stageA(An, 0, 0, 0);
      BAR();
      MFMAQ(0, 0);
      BAR();
      // ---- P6 ----
      readA(1, 1);
      if (!lastI) stageA(Ar, 0, t2, 1);
      else if (!lastAll) stageA(An, 0, 0, 1);
      BAR();
      MFMAQ(1, 0);
      if (lastAll) { VMCNT(0); } else { VMCNT(4); }
      BAR();
      // ---- P7 ----
      readB(1, 1);
      if (!lastI) stageB(0, t2, 0);
      else if (!lastAll) stageB(0, 0, 0);
      BAR();
      MFMAQ(1, 1);
      BAR();
      // ---- P8 ----
      readA(1, 0);
      if (!lastI) stageB(0, t2, 1);
      else if (!lastAll) stageB(0, 0, 1);
      BAR();
      MFMAQ(0, 1);
      WAIT_LB();
      BAR();
    }

    // epilogue for this rep (overlaps next rep's in-flight tile-0 loads)
    const int by = byg * REPS + rep;
    const int gr0 = by * BM + wr * WM + kh * 4;
    const int gc0 = bx * BN + wc * WN + lr;
#pragma unroll
    for (int m = 0; m < FM; ++m)
#pragma unroll
      for (int n = 0; n < FN; ++n) {
        const int c = gc0 + n * 16;
#pragma unroll
        for (int j = 0; j < 4; ++j) {
          const int r = gr0 + m * 16 + j;
          if constexpr (EPI == 6) {
            bf16* Cb = (bf16*)C0 + (size_t)bz * sCz;
            Cb[(size_t)r * ldc + c] = (bf16)__expf(acc[m][n][j]);
          } else {  // EPI == 3: f32 split-K partial
            float* Cf = (float*)(ks ? C1 : C0) + (size_t)bz * sCz;
            Cf[(size_t)r * ldc + c] = acc[m][n][j];
          }
          acc[m][n][j] = 0.f;           // re-zero for next rep (dead on last)
        }
      }
  }
#undef MFMAQ
#undef WAIT_LB
}

// ---------------- launch ----------------
extern "C" void kernel_launch(void* const* d_in, const int* in_sizes, int n_in,
                              void* d_out, int out_size, void* d_ws, size_t ws_size,
                              hipStream_t stream) {
  const float* x     = (const float*)d_in[0];
  const float* gamma = (const float*)d_in[1];
  const float* beta  = (const float*)d_in[2];
  const float* wq = (const float*)d_in[3];
  const float* bq = (const float*)d_in[4];
  const float* wk = (const float*)d_in[5];
  const float* bk = (const float*)d_in[6];
  const float* wv = (const float*)d_in[7];
  const float* bv = (const float*)d_in[8];
  const float* wo = (const float*)d_in[9];
  const float* bo = (const float*)d_in[10];
  float* out = (float*)d_out;
  char* ws = (char*)d_ws;

  float2* stats    = (float2*)(ws + OFF_STATS);
  bf16*   wot      = (bf16*)(ws + OFF_WOT);
  float*  bias_qkv = (float*)(ws + OFF_BIASQ);
  bf16*   wt_qkv   = (bf16*)(ws + OFF_WTQKV);
  bf16*   xn       = (bf16*)(ws + OFF_XN);
  bf16*   qkv      = (bf16*)(ws + OFF_QKV);
  bf16*   vt       = (bf16*)(ws + OFF_VT);
  bf16*   S        = (bf16*)(ws + OFF_S);
  float*  invl     = (float*)(ws + OFF_INVL);
  float*  p0       = (float*)(ws + OFF_P0);
  float*  p1       = (float*)(ws + OFF_P1);
  bf16*   attn     = (bf16*)(ws + OFF_ATTN);
  float2* gn_part  = (float2*)(ws + OFF_GNP);

  const float qscale = 0.04419417382415922f;  // 1/sqrt(512)

  prep_w_k<<<dim3(16, 16, 4), dim3(32, 8), 0, stream>>>(wq, wk, wv, wo, wt_qkv, wot, qscale);
  prep_bias_k<<<6, 256, 0, stream>>>(bq, bk, bv, bias_qkv, qscale);
  gn_part_k<<<1024, 256, 0, stream>>>(x, gn_part);
  gn_finish_k<<<1, 64, 0, stream>>>(gn_part, stats);
  gn_apply_k<<<2048, 256, 0, stream>>>(x, stats, gamma, beta, xn);

  // QKV: [8192,512] @ WT[1536,512]^T -> qkv [8192,1536]  (2-phase, verified)
  gemm_nt<128, 128, 1, 12, 64, 1><<<768, 256, 0, stream>>>(
      xn, 512, 0, wt_qkv, 512, 0, qkv, 1536, 0, 512 / 64, bias_qkv, nullptr);

  // scores+exp: per batch P[4096,4096] = exp(q @ k^T)
  // 8-phase 256^2, REPS=2 chained row-tiles -> 256 blocks = 1 block/CU
  gemm_8p<256, 256, 2, 4, 6, 16, 8, 2, 1, 2><<<256, 512, 0, stream>>>(
      qkv, 1536, 4096L * 1536, qkv + 512, 1536, 4096L * 1536,
      S, nullptr, 4096, 4096L * 4096, 512 / 64);

  // softmax denominators from the bf16-rounded P (consistent with PV operand)
  rowsum_k<<<8192, 256, 0, stream>>>(S, invl);

  transpose_v_k<<<dim3(128, 16, 2), dim3(32, 8), 0, stream>>>(qkv, vt);

  // PV: per batch [4096,512] = P @ VT^T  (8-phase 256x128, split-K=2 -> f32)
  gemm_8p<256, 128, 4, 2, 3, 4, 16, 2, 2, 1><<<256, 512, 0, stream>>>(
      S, 4096, 4096L * 4096, vt, 4096, 512L * 4096,
      p0, p1, 512, 4096L * 512, 2048 / 64);

  // reduce + normalize: attn = bf16((p0+p1) * inv_l[row])
  reduce_pv_k<<<2048, 256, 0, stream>>>(p0, p1, invl, attn);

  // out: [8192,512] = attn @ WOT^T + bo + inputs (fp32)
  gemm_nt<64, 128, 2, 4, 128, 1><<<512, 256, 0, stream>>>(
      attn, 512, 0, wot, 512, 0, out, 512, 0, 512 / 64, bo, x);
}